// Round 3
// baseline (277.542 us; speedup 1.0000x reference)
//
#include <hip/hip_runtime.h>
#include <math.h>

// ---------------------------------------------------------------------------
// BitNet-style MNIST forward, fully fused, STRICT-FP32, tie-neutralized
// act-quant (R14) + R15 (conflict-free strides) + R16 (float4 LDS, weights
// direct-from-global) + R17:
//  * fc section (stages E..H) runs ENTIRELY on wave 0 after a single
//    __syncthreads: intra-wave LDS ordering makes the ~20 fc barriers
//    unnecessary; waves 1-3 retire early. s_bc broadcasts replaced by
//    all-lanes-redundant compute (identical bits: same tree, same butterfly).
//  * v_pk_fma_f32 in conv inner loops (stages B,C): adjacent-ow pairs in
//    aligned f32x2 accumulators; kw=0/2 packed, kw=1 scalar. Per-output
//    chain order unchanged -> bit-identical.
//  * s_h2 channel stride 240->244 floats (976B = 80B mod 128 -> stage-D
//    reads spread over 8 bank-quads instead of 2).
//  * __launch_bounds__(256,4) + unroll-2 ic loop: VGPR<=128 keeps 4 blocks/CU
//    while letting weight loads pipeline ahead of the FMA stream.
// ---------------------------------------------------------------------------

#define OFF_W1   0        // 16 oc x 12      = 192   ([oc][k], k padded 9->12)
#define OFF_W1B  192      // 16 oc x 16 x 12 = 3072  ([oc][ic*12+k])
#define OFF_W2   3264     // 96*1*12*12 = 13824 (TRANSPOSED: [k=144][96 oc])
#define OFF_F1   17088    // 64*96      = 6144  (TRANSPOSED: [k=96][64 o])
#define OFF_F2   23232    // 64*64      = 4096  (TRANSPOSED: [k=64][64 o])
#define OFF_F3   27328    // 64*64      = 4096  (TRANSPOSED: [k=64][64 o])
#define OFF_FL   31424    // 10*64      = 640   (TRANSPOSED: [k=64][10 o])

#define EPS_TIE  3e-5f    // code-units half-width of the tie band

typedef float f32x2 __attribute__((ext_vector_type(2)));

// packed dual FMA, IEEE RN per lane-half — bit-identical to two v_fma_f32
__device__ __forceinline__ void pk_fma(f32x2& acc, f32x2 a, f32x2 w) {
    asm("v_pk_fma_f32 %0, %1, %2, %0" : "+v"(acc) : "v"(a), "v"(w));
}

// Tie-neutralized quantized real value for v >= 0 (post-ReLU / normed >= 0).
__device__ __forceinline__ float quantq(float v, float s) {
    const float u  = __fmul_rn(v, s);
    const float fl = floorf(u);
    const float fr = __fsub_rn(u, fl);                 // exact
    float q;
    if (fabsf(__fsub_rn(fr, 0.5f)) < EPS_TIE) q = __fadd_rn(fl, 0.5f);
    else                                      q = rintf(u);
    q = fminf(q, 127.f);
    return __fdiv_rn(q, s);
}

// numpy pairwise leaf (n <= 128): 8 unrolled accumulators over |p[i]|.
__device__ __forceinline__ float leaf_abs_sum(const float* __restrict__ p, int n) {
    float r[8];
    #pragma unroll
    for (int j = 0; j < 8; ++j) r[j] = fabsf(p[j]);
    const int nb = n & ~7;
    for (int i = 8; i < nb; i += 8) {
        #pragma unroll
        for (int j = 0; j < 8; ++j) r[j] = __fadd_rn(r[j], fabsf(p[i + j]));
    }
    float c = __fadd_rn(__fadd_rn(__fadd_rn(r[0], r[1]), __fadd_rn(r[2], r[3])),
                        __fadd_rn(__fadd_rn(r[4], r[5]), __fadd_rn(r[6], r[7])));
    for (int i = nb; i < n; ++i) c = __fadd_rn(c, fabsf(p[i]));
    return c;
}

// ---------------------------------------------------------------------------
// Weight quantization: 7 blocks, one per tensor. Values identical; only
// destination layouts changed (see R16 header).
// ---------------------------------------------------------------------------
__global__ __launch_bounds__(256) void wq_kernel(
    const float* __restrict__ w1, const float* __restrict__ w1b,
    const float* __restrict__ w2, const float* __restrict__ f1,
    const float* __restrict__ f2, const float* __restrict__ f3,
    const float* __restrict__ fl, float* __restrict__ ws)
{
    __shared__ float red[256];
    __shared__ float ls[128];
    const int blk = blockIdx.x, t = threadIdx.x;

    const float* src; int n; int mode; int off; int K; int W;
    switch (blk) {
        case 0:  src = w1;  n = 144;   mode = 0; off = OFF_W1;  K = 0;   W = 0;  break;
        case 1:  src = w1b; n = 2304;  mode = 0; off = OFF_W1B; K = 0;   W = 0;  break;
        case 2:  src = w2;  n = 13824; mode = 1; off = OFF_W2;  K = 144; W = 96; break;
        case 3:  src = f1;  n = 6144;  mode = 1; off = OFF_F1;  K = 96;  W = 64; break;
        case 4:  src = f2;  n = 4096;  mode = 1; off = OFF_F2;  K = 64;  W = 64; break;
        case 5:  src = f3;  n = 4096;  mode = 1; off = OFF_F3;  K = 64;  W = 64; break;
        default: src = fl;  n = 640;   mode = 1; off = OFF_FL;  K = 64;  W = 10; break;
    }

    if (mode == 0) {
        float p = 0.f;
        for (int i = t; i < n; i += 256) p = fmaxf(p, fabsf(src[i]));
        red[t] = p;
        __syncthreads();
        for (int s = 128; s > 0; s >>= 1) {
            if (t < s) red[t] = fmaxf(red[t], red[t + s]);
            __syncthreads();
        }
        const float s = __fdiv_rn(127.0f, fmaxf(red[0], 1e-5f));
        for (int i = t; i < n; i += 256) {
            float q = rintf(__fmul_rn(src[i], s));
            q = fminf(fmaxf(q, -128.f), 127.f);
            int d;
            if (blk == 0) d = (i / 9) * 12 + (i % 9);
            else          { const int oc = i / 144, k = i % 144;
                            d = oc * 192 + (k / 9) * 12 + (k % 9); }
            ws[off + d] = __fdiv_rn(q, s);
        }
    } else {
        int nleaf, loff, lsz;
        switch (n) {
            case 13824: nleaf = 128; loff = (t >> 1) * 216 + (t & 1) * 104;
                        lsz = (t & 1) ? 112 : 104; break;
            case 6144:  nleaf = 64;  loff = t * 96;  lsz = 96;  break;
            case 4096:  nleaf = 32;  loff = t * 128; lsz = 128; break;
            default:    nleaf = 8;   loff = t * 80;  lsz = 80;  break;  // 640
        }
        if (t < nleaf) ls[t] = leaf_abs_sum(src + loff, lsz);
        __syncthreads();
        for (int m = nleaf >> 1; m >= 1; m >>= 1) {
            float v = 0.f;
            if (t < m) v = __fadd_rn(ls[2 * t], ls[2 * t + 1]);
            __syncthreads();
            if (t < m) ls[t] = v;
            __syncthreads();
        }
        const float alpha = __fdiv_rn(ls[0], (float)n);
        for (int i = t; i < n; i += 256) {
            const float w = src[i];
            const float sg = (w > 0.f) ? 1.f : ((w < 0.f) ? -1.f : 0.f);
            const int d = (i % K) * W + (i / K);
            ws[off + d] = __fmul_rn(sg, alpha);
        }
    }
}

// ---------------------------------------------------------------------------
// Fused forward: one block (256 threads) per image, strict fp32.
// ---------------------------------------------------------------------------
#define H2S 244   // s_h2 channel stride in floats (976B = 80B mod 128 -> 8 quads)

__global__ __launch_bounds__(256, 4) void fused_kernel(
    const float* __restrict__ x, const float* __restrict__ ws,
    float* __restrict__ out)
{
    __shared__ __align__(16) float s_x[16][20];
    __shared__ __align__(16) float s_h1[16][14][20];
    __shared__ __align__(16) float s_h2f[16 * H2S];
    __shared__ float s_v96[96];
    __shared__ float s_t96[96];
    __shared__ float s_q[96];
    __shared__ float s_r8[8];

    const int b = blockIdx.x;
    const int t = threadIdx.x;

    // ---- Stage A: input act-quant (accumulation-free -> hard round) ----
    {
        const float v = x[b * 256 + t];
        float m = fabsf(v);
        #pragma unroll
        for (int msk = 8; msk >= 1; msk >>= 1) m = fmaxf(m, __shfl_xor(m, msk, 16));
        const float s = __fdiv_rn(127.0f, fmaxf(m, 1e-5f));
        float q = rintf(__fmul_rn(v, s));
        q = fminf(fmaxf(q, -128.f), 127.f);
        s_x[t >> 4][t & 15] = __fdiv_rn(q, s);
    }
    __syncthreads();

    // ---- Stage B: conv1 (1->16, 3x3) + ReLU + row quant (tie-neutral) ----
    if (t < 224) {
        const int oc = t / 14, oh = t % 14;
        const float* __restrict__ wg = ws + OFF_W1 + oc * 12;
        const float4 wv0 = *(const float4*)&wg[0];
        const float4 wv1 = *(const float4*)&wg[4];
        const float  w8  = wg[8];
        const float wr[9] = {wv0.x, wv0.y, wv0.z, wv0.w,
                             wv1.x, wv1.y, wv1.z, wv1.w, w8};
        f32x2 acc2[7];
        #pragma unroll
        for (int j = 0; j < 7; ++j) { acc2[j][0] = 0.f; acc2[j][1] = 0.f; }
        #pragma unroll
        for (int kh = 0; kh < 3; ++kh) {
            float A[16];
            *(float4*)&A[0]  = *(const float4*)&s_x[oh + kh][0];
            *(float4*)&A[4]  = *(const float4*)&s_x[oh + kh][4];
            *(float4*)&A[8]  = *(const float4*)&s_x[oh + kh][8];
            *(float4*)&A[12] = *(const float4*)&s_x[oh + kh][12];
            const float w0 = wr[kh * 3 + 0], w1k = wr[kh * 3 + 1], w2k = wr[kh * 3 + 2];
            f32x2 wp0; wp0[0] = w0;  wp0[1] = w0;
            f32x2 wp2; wp2[0] = w2k; wp2[1] = w2k;
            #pragma unroll
            for (int j = 0; j < 7; ++j) {           // kw = 0 (packed, aligned)
                f32x2 a; a[0] = A[2 * j]; a[1] = A[2 * j + 1];
                pk_fma(acc2[j], a, wp0);
            }
            #pragma unroll
            for (int j = 0; j < 7; ++j) {           // kw = 1 (scalar)
                acc2[j][0] = __fmaf_rn(A[2 * j + 1], w1k, acc2[j][0]);
                acc2[j][1] = __fmaf_rn(A[2 * j + 2], w1k, acc2[j][1]);
            }
            #pragma unroll
            for (int j = 0; j < 7; ++j) {           // kw = 2 (packed, aligned)
                f32x2 a; a[0] = A[2 * j + 2]; a[1] = A[2 * j + 3];
                pk_fma(acc2[j], a, wp2);
            }
        }
        float acc[14];
        #pragma unroll
        for (int j = 0; j < 7; ++j) { acc[2 * j] = acc2[j][0]; acc[2 * j + 1] = acc2[j][1]; }
        float mx = 0.f;
        #pragma unroll
        for (int ow = 0; ow < 14; ++ow) { acc[ow] = fmaxf(acc[ow], 0.f); mx = fmaxf(mx, acc[ow]); }
        const float s = __fdiv_rn(127.0f, fmaxf(mx, 1e-5f));
        float q[14];
        #pragma unroll
        for (int ow = 0; ow < 14; ++ow) q[ow] = quantq(acc[ow], s);
        *(float4*)&s_h1[oc][oh][0]  = *(const float4*)&q[0];
        *(float4*)&s_h1[oc][oh][4]  = *(const float4*)&q[4];
        *(float4*)&s_h1[oc][oh][8]  = *(const float4*)&q[8];
        *(float2*)&s_h1[oc][oh][12] = *(const float2*)&q[12];
    }
    __syncthreads();

    // ---- Stage C: conv1b (16->16, 3x3) + ReLU + row quant (tie-neutral) ----
    if (t < 192) {
        const int oc = t / 12, oh = t % 12;
        const float* __restrict__ wg = ws + OFF_W1B + oc * 192;
        f32x2 acc2[6];
        #pragma unroll
        for (int j = 0; j < 6; ++j) { acc2[j][0] = 0.f; acc2[j][1] = 0.f; }
        #pragma unroll 2
        for (int ic = 0; ic < 16; ++ic) {
            const float4 wv0 = *(const float4*)&wg[ic * 12];
            const float4 wv1 = *(const float4*)&wg[ic * 12 + 4];
            const float  w8  = wg[ic * 12 + 8];
            const float wr[9] = {wv0.x, wv0.y, wv0.z, wv0.w,
                                 wv1.x, wv1.y, wv1.z, wv1.w, w8};
            #pragma unroll
            for (int kh = 0; kh < 3; ++kh) {
                float A[14];
                *(float4*)&A[0]  = *(const float4*)&s_h1[ic][oh + kh][0];
                *(float4*)&A[4]  = *(const float4*)&s_h1[ic][oh + kh][4];
                *(float4*)&A[8]  = *(const float4*)&s_h1[ic][oh + kh][8];
                *(float2*)&A[12] = *(const float2*)&s_h1[ic][oh + kh][12];
                const float w0 = wr[kh * 3 + 0], w1k = wr[kh * 3 + 1], w2k = wr[kh * 3 + 2];
                f32x2 wp0; wp0[0] = w0;  wp0[1] = w0;
                f32x2 wp2; wp2[0] = w2k; wp2[1] = w2k;
                #pragma unroll
                for (int j = 0; j < 6; ++j) {       // kw = 0 (packed)
                    f32x2 a; a[0] = A[2 * j]; a[1] = A[2 * j + 1];
                    pk_fma(acc2[j], a, wp0);
                }
                #pragma unroll
                for (int j = 0; j < 6; ++j) {       // kw = 1 (scalar)
                    acc2[j][0] = __fmaf_rn(A[2 * j + 1], w1k, acc2[j][0]);
                    acc2[j][1] = __fmaf_rn(A[2 * j + 2], w1k, acc2[j][1]);
                }
                #pragma unroll
                for (int j = 0; j < 6; ++j) {       // kw = 2 (packed)
                    f32x2 a; a[0] = A[2 * j + 2]; a[1] = A[2 * j + 3];
                    pk_fma(acc2[j], a, wp2);
                }
            }
        }
        float acc[12];
        #pragma unroll
        for (int j = 0; j < 6; ++j) { acc[2 * j] = acc2[j][0]; acc[2 * j + 1] = acc2[j][1]; }
        float mx = 0.f;
        #pragma unroll
        for (int ow = 0; ow < 12; ++ow) { acc[ow] = fmaxf(acc[ow], 0.f); mx = fmaxf(mx, acc[ow]); }
        const float s = __fdiv_rn(127.0f, fmaxf(mx, 1e-5f));
        float q[12];
        #pragma unroll
        for (int ow = 0; ow < 12; ++ow) q[ow] = quantq(acc[ow], s);
        *(float4*)&s_h2f[oc * H2S + oh * 20 + 0] = *(const float4*)&q[0];
        *(float4*)&s_h2f[oc * H2S + oh * 20 + 4] = *(const float4*)&q[4];
        *(float4*)&s_h2f[oc * H2S + oh * 20 + 8] = *(const float4*)&q[8];
    }
    __syncthreads();

    // ---- Stage D: conv2 grouped binary (16 groups x 6 oc, 12x12) + ReLU ----
    if (t < 96) {
        const int g = t / 6;
        const float* __restrict__ wp = ws + OFF_W2;  // transposed: [k=144][96 oc]
        float acc = 0.f;
        #pragma unroll
        for (int r = 0; r < 12; ++r) {
            float A[12];
            *(float4*)&A[0] = *(const float4*)&s_h2f[g * H2S + r * 20 + 0];
            *(float4*)&A[4] = *(const float4*)&s_h2f[g * H2S + r * 20 + 4];
            *(float4*)&A[8] = *(const float4*)&s_h2f[g * H2S + r * 20 + 8];
            #pragma unroll
            for (int c = 0; c < 12; ++c)
                acc = __fmaf_rn(A[c], wp[(r * 12 + c) * 96 + t], acc);
        }
        s_v96[t] = fmaxf(acc, 0.f);
    }
    __syncthreads();

    // ================= fc section: ENTIRELY wave 0, no barriers =============
    if (t >= 64) return;   // waves 1-3 retire

    // ---- Stage E: fc1 (96->64) ----
    float u;   // current activation vector element (lane t holds element t)
    {
        const float va = s_v96[t];
        const float vb = (t < 32) ? s_v96[64 + t] : 0.f;
        s_t96[t] = __fmul_rn(va, va);
        if (t < 32) s_t96[64 + t] = __fmul_rn(vb, vb);
        if (t < 8) {
            float r = s_t96[t];
            for (int i = 8; i < 96; i += 8) r = __fadd_rn(r, s_t96[i + t]);
            s_r8[t] = r;
        }
        // all lanes redundantly compute the tree -> identical bits, no s_bc trip
        const float c = __fadd_rn(
            __fadd_rn(__fadd_rn(s_r8[0], s_r8[1]), __fadd_rn(s_r8[2], s_r8[3])),
            __fadd_rn(__fadd_rn(s_r8[4], s_r8[5]), __fadd_rn(s_r8[6], s_r8[7])));
        const float mean = __fdiv_rn(c, 96.0f);
        const float bc1 = __fdiv_rn(1.0f, __fsqrt_rn(__fadd_rn(mean, 1e-6f)));
        const float n0 = __fmul_rn(va, bc1);
        const float n1 = __fmul_rn(vb, bc1);       // valid for t<32
        float m = n0;
        if (t < 32) m = fmaxf(m, n1);
        #pragma unroll
        for (int msk = 32; msk >= 1; msk >>= 1) m = fmaxf(m, __shfl_xor(m, msk, 64));
        const float s2 = __fdiv_rn(127.0f, fmaxf(m, 1e-5f));
        s_q[t] = quantq(n0, s2);
        if (t < 32) s_q[64 + t] = quantq(n1, s2);
        const float* __restrict__ wp = ws + OFF_F1;  // [k=96][64 o]
        float acc = 0.f;
        for (int k = 0; k < 96; ++k) acc = __fmaf_rn(s_q[k], wp[k * 64 + t], acc);
        u = fmaxf(acc, 0.f);
    }

    // ---- Stages F,G: fc2, fc3 (64->64) ----
    #pragma unroll 1
    for (int stage = 0; stage < 2; ++stage) {
        const int woff = stage == 0 ? OFF_F2 : OFF_F3;
        s_t96[t] = __fmul_rn(u, u);
        if (t < 8) {
            float r = s_t96[t];
            for (int i = 8; i < 64; i += 8) r = __fadd_rn(r, s_t96[i + t]);
            s_r8[t] = r;
        }
        const float c = __fadd_rn(
            __fadd_rn(__fadd_rn(s_r8[0], s_r8[1]), __fadd_rn(s_r8[2], s_r8[3])),
            __fadd_rn(__fadd_rn(s_r8[4], s_r8[5]), __fadd_rn(s_r8[6], s_r8[7])));
        const float mean = __fdiv_rn(c, 64.0f);
        const float bc1 = __fdiv_rn(1.0f, __fsqrt_rn(__fadd_rn(mean, 1e-6f)));
        const float n0 = __fmul_rn(u, bc1);
        float m = n0;
        #pragma unroll
        for (int msk = 32; msk >= 1; msk >>= 1) m = fmaxf(m, __shfl_xor(m, msk, 64));
        const float s2 = __fdiv_rn(127.0f, fmaxf(m, 1e-5f));
        s_q[t] = quantq(n0, s2);
        const float* __restrict__ wp = ws + woff;    // [k=64][64 o]
        float acc = 0.f;
        for (int k = 0; k < 64; ++k) acc = __fmaf_rn(s_q[k], wp[k * 64 + t], acc);
        u = fmaxf(acc, 0.f);
    }

    // ---- Stage H: fcl (64->10), no ReLU ----
    {
        s_t96[t] = __fmul_rn(u, u);
        if (t < 8) {
            float r = s_t96[t];
            for (int i = 8; i < 64; i += 8) r = __fadd_rn(r, s_t96[i + t]);
            s_r8[t] = r;
        }
        const float c = __fadd_rn(
            __fadd_rn(__fadd_rn(s_r8[0], s_r8[1]), __fadd_rn(s_r8[2], s_r8[3])),
            __fadd_rn(__fadd_rn(s_r8[4], s_r8[5]), __fadd_rn(s_r8[6], s_r8[7])));
        const float mean = __fdiv_rn(c, 64.0f);
        const float bc1 = __fdiv_rn(1.0f, __fsqrt_rn(__fadd_rn(mean, 1e-6f)));
        const float n0 = __fmul_rn(u, bc1);
        float m = n0;
        #pragma unroll
        for (int msk = 32; msk >= 1; msk >>= 1) m = fmaxf(m, __shfl_xor(m, msk, 64));
        const float s2 = __fdiv_rn(127.0f, fmaxf(m, 1e-5f));
        s_q[t] = quantq(n0, s2);
        const int to = (t < 10) ? t : 9;             // clamp: avoid OOB reads
        const float* __restrict__ wp = ws + OFF_FL;  // [k=64][10 o]
        float acc = 0.f;
        for (int k = 0; k < 64; ++k) acc = __fmaf_rn(s_q[k], wp[k * 10 + to], acc);
        if (t < 10) out[b * 10 + t] = acc;
    }
}

extern "C" void kernel_launch(void* const* d_in, const int* in_sizes, int n_in,
                              void* d_out, int out_size, void* d_ws, size_t ws_size,
                              hipStream_t stream) {
    const float* x   = (const float*)d_in[0];
    const float* w1  = (const float*)d_in[1];
    const float* w1b = (const float*)d_in[2];
    const float* w2  = (const float*)d_in[3];
    const float* f1  = (const float*)d_in[4];
    const float* f2  = (const float*)d_in[5];
    const float* f3  = (const float*)d_in[6];
    const float* fl  = (const float*)d_in[7];
    float* out = (float*)d_out;
    float* ws  = (float*)d_ws;

    const int B = in_sizes[0] / 256;  // 8192

    wq_kernel<<<7, 256, 0, stream>>>(w1, w1b, w2, f1, f2, f3, fl, ws);
    fused_kernel<<<B, 256, 0, stream>>>(x, ws, out);
}

// Round 5
// 273.249 us; speedup vs baseline: 1.0157x; 1.0157x over previous
//
#include <hip/hip_runtime.h>
#include <math.h>

// ---------------------------------------------------------------------------
// BitNet-style MNIST forward, fully fused, STRICT-FP32, tie-neutralized
// act-quant (R14) + R15/R16 layout work + R17 (barrier-free wave-0 fc) + R19:
//  * R18 (XOR-swizzled s_h2 + s_t96/s_q union) FAILED correctness on HW
//    despite on-paper proofs; both reverted. Do not re-attempt without a
//    way to isolate which half was wrong.
//  * Same 5-blocks/CU goal achieved with proven techniques only:
//    - fc section: R17 verbatim (separate s_t96/s_q arrays).
//    - s_h2 compact ODD-STRIDE scalar layout: idx = g*156 + oh*13 + c
//      (9,984 B; stride-13 rows, channel stride 156 = 28 mod 32 -> stage-D
//      lanes (11 distinct g) spread across banks, only (g,g+8) 2-way = free.
//      Scalar LDS writes/reads; R16 proved LDS throughput non-critical.)
//  * LDS total 30,368 B -> 5 blocks/CU (was 36,352 -> 4). Kernel is
//    latency-bound (VALU ~55%, HBM 0.3%); +25% resident waves is the lever.
// ---------------------------------------------------------------------------

#define OFF_W1   0        // 16 oc x 12      = 192   ([oc][k], k padded 9->12)
#define OFF_W1B  192      // 16 oc x 16 x 12 = 3072  ([oc][ic*12+k])
#define OFF_W2   3264     // 96*1*12*12 = 13824 (TRANSPOSED: [k=144][96 oc])
#define OFF_F1   17088    // 64*96      = 6144  (TRANSPOSED: [k=96][64 o])
#define OFF_F2   23232    // 64*64      = 4096  (TRANSPOSED: [k=64][64 o])
#define OFF_F3   27328    // 64*64      = 4096  (TRANSPOSED: [k=64][64 o])
#define OFF_FL   31424    // 10*64      = 640   (TRANSPOSED: [k=64][10 o])

#define EPS_TIE  3e-5f    // code-units half-width of the tie band

// Tie-neutralized quantized real value for v >= 0 (post-ReLU / normed >= 0).
__device__ __forceinline__ float quantq(float v, float s) {
    const float u  = __fmul_rn(v, s);
    const float fl = floorf(u);
    const float fr = __fsub_rn(u, fl);                 // exact
    float q;
    if (fabsf(__fsub_rn(fr, 0.5f)) < EPS_TIE) q = __fadd_rn(fl, 0.5f);
    else                                      q = rintf(u);
    q = fminf(q, 127.f);
    return __fdiv_rn(q, s);
}

// numpy pairwise leaf (n <= 128): 8 unrolled accumulators over |p[i]|.
__device__ __forceinline__ float leaf_abs_sum(const float* __restrict__ p, int n) {
    float r[8];
    #pragma unroll
    for (int j = 0; j < 8; ++j) r[j] = fabsf(p[j]);
    const int nb = n & ~7;
    for (int i = 8; i < nb; i += 8) {
        #pragma unroll
        for (int j = 0; j < 8; ++j) r[j] = __fadd_rn(r[j], fabsf(p[i + j]));
    }
    float c = __fadd_rn(__fadd_rn(__fadd_rn(r[0], r[1]), __fadd_rn(r[2], r[3])),
                        __fadd_rn(__fadd_rn(r[4], r[5]), __fadd_rn(r[6], r[7])));
    for (int i = nb; i < n; ++i) c = __fadd_rn(c, fabsf(p[i]));
    return c;
}

// ---------------------------------------------------------------------------
// Weight quantization: 7 blocks, one per tensor. Values identical; only
// destination layouts changed (see R16 header).
// ---------------------------------------------------------------------------
__global__ __launch_bounds__(256) void wq_kernel(
    const float* __restrict__ w1, const float* __restrict__ w1b,
    const float* __restrict__ w2, const float* __restrict__ f1,
    const float* __restrict__ f2, const float* __restrict__ f3,
    const float* __restrict__ fl, float* __restrict__ ws)
{
    __shared__ float red[256];
    __shared__ float ls[128];
    const int blk = blockIdx.x, t = threadIdx.x;

    const float* src; int n; int mode; int off; int K; int W;
    switch (blk) {
        case 0:  src = w1;  n = 144;   mode = 0; off = OFF_W1;  K = 0;   W = 0;  break;
        case 1:  src = w1b; n = 2304;  mode = 0; off = OFF_W1B; K = 0;   W = 0;  break;
        case 2:  src = w2;  n = 13824; mode = 1; off = OFF_W2;  K = 144; W = 96; break;
        case 3:  src = f1;  n = 6144;  mode = 1; off = OFF_F1;  K = 96;  W = 64; break;
        case 4:  src = f2;  n = 4096;  mode = 1; off = OFF_F2;  K = 64;  W = 64; break;
        case 5:  src = f3;  n = 4096;  mode = 1; off = OFF_F3;  K = 64;  W = 64; break;
        default: src = fl;  n = 640;   mode = 1; off = OFF_FL;  K = 64;  W = 10; break;
    }

    if (mode == 0) {
        float p = 0.f;
        for (int i = t; i < n; i += 256) p = fmaxf(p, fabsf(src[i]));
        red[t] = p;
        __syncthreads();
        for (int s = 128; s > 0; s >>= 1) {
            if (t < s) red[t] = fmaxf(red[t], red[t + s]);
            __syncthreads();
        }
        const float s = __fdiv_rn(127.0f, fmaxf(red[0], 1e-5f));
        for (int i = t; i < n; i += 256) {
            float q = rintf(__fmul_rn(src[i], s));
            q = fminf(fmaxf(q, -128.f), 127.f);
            int d;
            if (blk == 0) d = (i / 9) * 12 + (i % 9);
            else          { const int oc = i / 144, k = i % 144;
                            d = oc * 192 + (k / 9) * 12 + (k % 9); }
            ws[off + d] = __fdiv_rn(q, s);
        }
    } else {
        int nleaf, loff, lsz;
        switch (n) {
            case 13824: nleaf = 128; loff = (t >> 1) * 216 + (t & 1) * 104;
                        lsz = (t & 1) ? 112 : 104; break;
            case 6144:  nleaf = 64;  loff = t * 96;  lsz = 96;  break;
            case 4096:  nleaf = 32;  loff = t * 128; lsz = 128; break;
            default:    nleaf = 8;   loff = t * 80;  lsz = 80;  break;  // 640
        }
        if (t < nleaf) ls[t] = leaf_abs_sum(src + loff, lsz);
        __syncthreads();
        for (int m = nleaf >> 1; m >= 1; m >>= 1) {
            float v = 0.f;
            if (t < m) v = __fadd_rn(ls[2 * t], ls[2 * t + 1]);
            __syncthreads();
            if (t < m) ls[t] = v;
            __syncthreads();
        }
        const float alpha = __fdiv_rn(ls[0], (float)n);
        for (int i = t; i < n; i += 256) {
            const float w = src[i];
            const float sg = (w > 0.f) ? 1.f : ((w < 0.f) ? -1.f : 0.f);
            const int d = (i % K) * W + (i / K);
            ws[off + d] = __fmul_rn(sg, alpha);
        }
    }
}

// ---------------------------------------------------------------------------
// Fused forward: one block (256 threads) per image, strict fp32.
// LDS total 30,368 B -> 5 blocks/CU.
// ---------------------------------------------------------------------------
__global__ __launch_bounds__(256) void fused_kernel(
    const float* __restrict__ x, const float* __restrict__ ws,
    float* __restrict__ out)
{
    __shared__ __align__(16) float s_x[16][20];        //  1280 B
    __shared__ __align__(16) float s_h1[16][14][20];   // 17920 B
    __shared__ float s_h2[16 * 156];                   //  9984 B (stride-13 rows)
    __shared__ float s_v96[96];                        //   384 B
    __shared__ float s_t96[96];                        //   384 B
    __shared__ float s_q[96];                          //   384 B
    __shared__ float s_r8[8];                          //    32 B

    const int b = blockIdx.x;
    const int t = threadIdx.x;

    // ---- Stage A: input act-quant (accumulation-free -> hard round) ----
    {
        const float v = x[b * 256 + t];
        float m = fabsf(v);
        #pragma unroll
        for (int msk = 8; msk >= 1; msk >>= 1) m = fmaxf(m, __shfl_xor(m, msk, 16));
        const float s = __fdiv_rn(127.0f, fmaxf(m, 1e-5f));
        float q = rintf(__fmul_rn(v, s));
        q = fminf(fmaxf(q, -128.f), 127.f);
        s_x[t >> 4][t & 15] = __fdiv_rn(q, s);
    }
    __syncthreads();

    // ---- Stage B: conv1 (1->16, 3x3) + ReLU + row quant (tie-neutral) ----
    if (t < 224) {
        const int oc = t / 14, oh = t % 14;
        const float* __restrict__ wg = ws + OFF_W1 + oc * 12;
        const float4 wv0 = *(const float4*)&wg[0];
        const float4 wv1 = *(const float4*)&wg[4];
        const float  w8  = wg[8];
        const float wr[9] = {wv0.x, wv0.y, wv0.z, wv0.w,
                             wv1.x, wv1.y, wv1.z, wv1.w, w8};
        float acc[14];
        #pragma unroll
        for (int ow = 0; ow < 14; ++ow) acc[ow] = 0.f;
        #pragma unroll
        for (int kh = 0; kh < 3; ++kh) {
            float A[16];
            *(float4*)&A[0]  = *(const float4*)&s_x[oh + kh][0];
            *(float4*)&A[4]  = *(const float4*)&s_x[oh + kh][4];
            *(float4*)&A[8]  = *(const float4*)&s_x[oh + kh][8];
            *(float4*)&A[12] = *(const float4*)&s_x[oh + kh][12];
            #pragma unroll
            for (int kw = 0; kw < 3; ++kw) {
                const float wk = wr[kh * 3 + kw];
                #pragma unroll
                for (int ow = 0; ow < 14; ++ow)
                    acc[ow] = __fmaf_rn(A[ow + kw], wk, acc[ow]);
            }
        }
        float mx = 0.f;
        #pragma unroll
        for (int ow = 0; ow < 14; ++ow) { acc[ow] = fmaxf(acc[ow], 0.f); mx = fmaxf(mx, acc[ow]); }
        const float s = __fdiv_rn(127.0f, fmaxf(mx, 1e-5f));
        float q[14];
        #pragma unroll
        for (int ow = 0; ow < 14; ++ow) q[ow] = quantq(acc[ow], s);
        *(float4*)&s_h1[oc][oh][0]  = *(const float4*)&q[0];
        *(float4*)&s_h1[oc][oh][4]  = *(const float4*)&q[4];
        *(float4*)&s_h1[oc][oh][8]  = *(const float4*)&q[8];
        *(float2*)&s_h1[oc][oh][12] = *(const float2*)&q[12];
    }
    __syncthreads();

    // ---- Stage C: conv1b (16->16, 3x3) + ReLU + row quant (tie-neutral) ----
    if (t < 192) {
        const int oc = t / 12, oh = t % 12;
        const float* __restrict__ wg = ws + OFF_W1B + oc * 192;
        float acc[12];
        #pragma unroll
        for (int i = 0; i < 12; ++i) acc[i] = 0.f;
        for (int ic = 0; ic < 16; ++ic) {
            const float4 wv0 = *(const float4*)&wg[ic * 12];
            const float4 wv1 = *(const float4*)&wg[ic * 12 + 4];
            const float  w8  = wg[ic * 12 + 8];
            const float wr[9] = {wv0.x, wv0.y, wv0.z, wv0.w,
                                 wv1.x, wv1.y, wv1.z, wv1.w, w8};
            #pragma unroll
            for (int kh = 0; kh < 3; ++kh) {
                float A[14];
                *(float4*)&A[0]  = *(const float4*)&s_h1[ic][oh + kh][0];
                *(float4*)&A[4]  = *(const float4*)&s_h1[ic][oh + kh][4];
                *(float4*)&A[8]  = *(const float4*)&s_h1[ic][oh + kh][8];
                *(float2*)&A[12] = *(const float2*)&s_h1[ic][oh + kh][12];
                #pragma unroll
                for (int kw = 0; kw < 3; ++kw) {
                    const float w = wr[kh * 3 + kw];
                    #pragma unroll
                    for (int ow = 0; ow < 12; ++ow)
                        acc[ow] = __fmaf_rn(A[ow + kw], w, acc[ow]);
                }
            }
        }
        float mx = 0.f;
        #pragma unroll
        for (int ow = 0; ow < 12; ++ow) { acc[ow] = fmaxf(acc[ow], 0.f); mx = fmaxf(mx, acc[ow]); }
        const float s = __fdiv_rn(127.0f, fmaxf(mx, 1e-5f));
        const int hb = oc * 156 + oh * 13;
        #pragma unroll
        for (int ow = 0; ow < 12; ++ow)
            s_h2[hb + ow] = quantq(acc[ow], s);
    }
    __syncthreads();

    // ---- Stage D: conv2 grouped binary (16 groups x 6 oc, 12x12) + ReLU ----
    if (t < 96) {
        const int g = t / 6;
        const float* __restrict__ wp = ws + OFF_W2;  // transposed: [k=144][96 oc]
        float acc = 0.f;
        #pragma unroll
        for (int r = 0; r < 12; ++r) {
            const int hb = g * 156 + r * 13;
            #pragma unroll
            for (int c = 0; c < 12; ++c)
                acc = __fmaf_rn(s_h2[hb + c], wp[(r * 12 + c) * 96 + t], acc);
        }
        s_v96[t] = fmaxf(acc, 0.f);
    }
    __syncthreads();

    // ================= fc section: ENTIRELY wave 0, no barriers =============
    if (t >= 64) return;   // waves 1-3 retire

    // ---- Stage E: fc1 (96->64) ----
    float u;   // current activation vector element (lane t holds element t)
    {
        const float va = s_v96[t];
        const float vb = (t < 32) ? s_v96[64 + t] : 0.f;
        s_t96[t] = __fmul_rn(va, va);
        if (t < 32) s_t96[64 + t] = __fmul_rn(vb, vb);
        if (t < 8) {
            float r = s_t96[t];
            for (int i = 8; i < 96; i += 8) r = __fadd_rn(r, s_t96[i + t]);
            s_r8[t] = r;
        }
        // all lanes redundantly compute the tree -> identical bits, no broadcast
        const float c = __fadd_rn(
            __fadd_rn(__fadd_rn(s_r8[0], s_r8[1]), __fadd_rn(s_r8[2], s_r8[3])),
            __fadd_rn(__fadd_rn(s_r8[4], s_r8[5]), __fadd_rn(s_r8[6], s_r8[7])));
        const float mean = __fdiv_rn(c, 96.0f);
        const float bc1 = __fdiv_rn(1.0f, __fsqrt_rn(__fadd_rn(mean, 1e-6f)));
        const float n0 = __fmul_rn(va, bc1);
        const float n1 = __fmul_rn(vb, bc1);       // valid for t<32
        float m = n0;
        if (t < 32) m = fmaxf(m, n1);
        #pragma unroll
        for (int msk = 32; msk >= 1; msk >>= 1) m = fmaxf(m, __shfl_xor(m, msk, 64));
        const float s2 = __fdiv_rn(127.0f, fmaxf(m, 1e-5f));
        s_q[t] = quantq(n0, s2);
        if (t < 32) s_q[64 + t] = quantq(n1, s2);
        const float* __restrict__ wp = ws + OFF_F1;  // [k=96][64 o]
        float acc = 0.f;
        for (int k = 0; k < 96; ++k) acc = __fmaf_rn(s_q[k], wp[k * 64 + t], acc);
        u = fmaxf(acc, 0.f);
    }

    // ---- Stages F,G: fc2, fc3 (64->64) ----
    #pragma unroll 1
    for (int stage = 0; stage < 2; ++stage) {
        const int woff = stage == 0 ? OFF_F2 : OFF_F3;
        s_t96[t] = __fmul_rn(u, u);
        if (t < 8) {
            float r = s_t96[t];
            for (int i = 8; i < 64; i += 8) r = __fadd_rn(r, s_t96[i + t]);
            s_r8[t] = r;
        }
        const float c = __fadd_rn(
            __fadd_rn(__fadd_rn(s_r8[0], s_r8[1]), __fadd_rn(s_r8[2], s_r8[3])),
            __fadd_rn(__fadd_rn(s_r8[4], s_r8[5]), __fadd_rn(s_r8[6], s_r8[7])));
        const float mean = __fdiv_rn(c, 64.0f);
        const float bc1 = __fdiv_rn(1.0f, __fsqrt_rn(__fadd_rn(mean, 1e-6f)));
        const float n0 = __fmul_rn(u, bc1);
        float m = n0;
        #pragma unroll
        for (int msk = 32; msk >= 1; msk >>= 1) m = fmaxf(m, __shfl_xor(m, msk, 64));
        const float s2 = __fdiv_rn(127.0f, fmaxf(m, 1e-5f));
        s_q[t] = quantq(n0, s2);
        const float* __restrict__ wp = ws + woff;    // [k=64][64 o]
        float acc = 0.f;
        for (int k = 0; k < 64; ++k) acc = __fmaf_rn(s_q[k], wp[k * 64 + t], acc);
        u = fmaxf(acc, 0.f);
    }

    // ---- Stage H: fcl (64->10), no ReLU ----
    {
        s_t96[t] = __fmul_rn(u, u);
        if (t < 8) {
            float r = s_t96[t];
            for (int i = 8; i < 64; i += 8) r = __fadd_rn(r, s_t96[i + t]);
            s_r8[t] = r;
        }
        const float c = __fadd_rn(
            __fadd_rn(__fadd_rn(s_r8[0], s_r8[1]), __fadd_rn(s_r8[2], s_r8[3])),
            __fadd_rn(__fadd_rn(s_r8[4], s_r8[5]), __fadd_rn(s_r8[6], s_r8[7])));
        const float mean = __fdiv_rn(c, 64.0f);
        const float bc1 = __fdiv_rn(1.0f, __fsqrt_rn(__fadd_rn(mean, 1e-6f)));
        const float n0 = __fmul_rn(u, bc1);
        float m = n0;
        #pragma unroll
        for (int msk = 32; msk >= 1; msk >>= 1) m = fmaxf(m, __shfl_xor(m, msk, 64));
        const float s2 = __fdiv_rn(127.0f, fmaxf(m, 1e-5f));
        s_q[t] = quantq(n0, s2);
        const int to = (t < 10) ? t : 9;             // clamp: avoid OOB reads
        const float* __restrict__ wp = ws + OFF_FL;  // [k=64][10 o]
        float acc = 0.f;
        for (int k = 0; k < 64; ++k) acc = __fmaf_rn(s_q[k], wp[k * 10 + to], acc);
        if (t < 10) out[b * 10 + t] = acc;
    }
}

extern "C" void kernel_launch(void* const* d_in, const int* in_sizes, int n_in,
                              void* d_out, int out_size, void* d_ws, size_t ws_size,
                              hipStream_t stream) {
    const float* x   = (const float*)d_in[0];
    const float* w1  = (const float*)d_in[1];
    const float* w1b = (const float*)d_in[2];
    const float* w2  = (const float*)d_in[3];
    const float* f1  = (const float*)d_in[4];
    const float* f2  = (const float*)d_in[5];
    const float* f3  = (const float*)d_in[6];
    const float* fl  = (const float*)d_in[7];
    float* out = (float*)d_out;
    float* ws  = (float*)d_ws;

    const int B = in_sizes[0] / 256;  // 8192

    wq_kernel<<<7, 256, 0, stream>>>(w1, w1b, w2, f1, f2, f3, fl, ws);
    fused_kernel<<<B, 256, 0, stream>>>(x, ws, out);
}

// Round 6
// 252.715 us; speedup vs baseline: 1.0982x; 1.0813x over previous
//
#include <hip/hip_runtime.h>
#include <math.h>

// ---------------------------------------------------------------------------
// BitNet-style MNIST forward, fully fused, STRICT-FP32, tie-neutralized
// act-quant (R14) + R15/R16 layout work + R17 (barrier-free wave-0 fc) +
// R19 (30,368 B LDS -> 5 blocks/CU feasible) + R20:
//  * __launch_bounds__(256, 8) on fused_kernel. R19's VGPR count drifted
//    64 -> 68, crossing the measured 64-VGPR occupancy step (waves/SIMD
//    halve at 64/128/256) -> the LDS shrink's 5th block/CU never became
//    resident (measured occupancy FELL). Capping at 512/8 = 64 VGPRs
//    restores 8 waves/SIMD eligibility; occupancy is then purely
//    LDS-capped at 5 blocks/CU = 20 waves (+25% vs 16).
//    R16 compiled this code shape at 60 VGPRs naturally -> no spill expected.
// ---------------------------------------------------------------------------

#define OFF_W1   0        // 16 oc x 12      = 192   ([oc][k], k padded 9->12)
#define OFF_W1B  192      // 16 oc x 16 x 12 = 3072  ([oc][ic*12+k])
#define OFF_W2   3264     // 96*1*12*12 = 13824 (TRANSPOSED: [k=144][96 oc])
#define OFF_F1   17088    // 64*96      = 6144  (TRANSPOSED: [k=96][64 o])
#define OFF_F2   23232    // 64*64      = 4096  (TRANSPOSED: [k=64][64 o])
#define OFF_F3   27328    // 64*64      = 4096  (TRANSPOSED: [k=64][64 o])
#define OFF_FL   31424    // 10*64      = 640   (TRANSPOSED: [k=64][10 o])

#define EPS_TIE  3e-5f    // code-units half-width of the tie band

// Tie-neutralized quantized real value for v >= 0 (post-ReLU / normed >= 0).
__device__ __forceinline__ float quantq(float v, float s) {
    const float u  = __fmul_rn(v, s);
    const float fl = floorf(u);
    const float fr = __fsub_rn(u, fl);                 // exact
    float q;
    if (fabsf(__fsub_rn(fr, 0.5f)) < EPS_TIE) q = __fadd_rn(fl, 0.5f);
    else                                      q = rintf(u);
    q = fminf(q, 127.f);
    return __fdiv_rn(q, s);
}

// numpy pairwise leaf (n <= 128): 8 unrolled accumulators over |p[i]|.
__device__ __forceinline__ float leaf_abs_sum(const float* __restrict__ p, int n) {
    float r[8];
    #pragma unroll
    for (int j = 0; j < 8; ++j) r[j] = fabsf(p[j]);
    const int nb = n & ~7;
    for (int i = 8; i < nb; i += 8) {
        #pragma unroll
        for (int j = 0; j < 8; ++j) r[j] = __fadd_rn(r[j], fabsf(p[i + j]));
    }
    float c = __fadd_rn(__fadd_rn(__fadd_rn(r[0], r[1]), __fadd_rn(r[2], r[3])),
                        __fadd_rn(__fadd_rn(r[4], r[5]), __fadd_rn(r[6], r[7])));
    for (int i = nb; i < n; ++i) c = __fadd_rn(c, fabsf(p[i]));
    return c;
}

// ---------------------------------------------------------------------------
// Weight quantization: 7 blocks, one per tensor. Values identical; only
// destination layouts changed (see R16 header).
// ---------------------------------------------------------------------------
__global__ __launch_bounds__(256) void wq_kernel(
    const float* __restrict__ w1, const float* __restrict__ w1b,
    const float* __restrict__ w2, const float* __restrict__ f1,
    const float* __restrict__ f2, const float* __restrict__ f3,
    const float* __restrict__ fl, float* __restrict__ ws)
{
    __shared__ float red[256];
    __shared__ float ls[128];
    const int blk = blockIdx.x, t = threadIdx.x;

    const float* src; int n; int mode; int off; int K; int W;
    switch (blk) {
        case 0:  src = w1;  n = 144;   mode = 0; off = OFF_W1;  K = 0;   W = 0;  break;
        case 1:  src = w1b; n = 2304;  mode = 0; off = OFF_W1B; K = 0;   W = 0;  break;
        case 2:  src = w2;  n = 13824; mode = 1; off = OFF_W2;  K = 144; W = 96; break;
        case 3:  src = f1;  n = 6144;  mode = 1; off = OFF_F1;  K = 96;  W = 64; break;
        case 4:  src = f2;  n = 4096;  mode = 1; off = OFF_F2;  K = 64;  W = 64; break;
        case 5:  src = f3;  n = 4096;  mode = 1; off = OFF_F3;  K = 64;  W = 64; break;
        default: src = fl;  n = 640;   mode = 1; off = OFF_FL;  K = 64;  W = 10; break;
    }

    if (mode == 0) {
        float p = 0.f;
        for (int i = t; i < n; i += 256) p = fmaxf(p, fabsf(src[i]));
        red[t] = p;
        __syncthreads();
        for (int s = 128; s > 0; s >>= 1) {
            if (t < s) red[t] = fmaxf(red[t], red[t + s]);
            __syncthreads();
        }
        const float s = __fdiv_rn(127.0f, fmaxf(red[0], 1e-5f));
        for (int i = t; i < n; i += 256) {
            float q = rintf(__fmul_rn(src[i], s));
            q = fminf(fmaxf(q, -128.f), 127.f);
            int d;
            if (blk == 0) d = (i / 9) * 12 + (i % 9);
            else          { const int oc = i / 144, k = i % 144;
                            d = oc * 192 + (k / 9) * 12 + (k % 9); }
            ws[off + d] = __fdiv_rn(q, s);
        }
    } else {
        int nleaf, loff, lsz;
        switch (n) {
            case 13824: nleaf = 128; loff = (t >> 1) * 216 + (t & 1) * 104;
                        lsz = (t & 1) ? 112 : 104; break;
            case 6144:  nleaf = 64;  loff = t * 96;  lsz = 96;  break;
            case 4096:  nleaf = 32;  loff = t * 128; lsz = 128; break;
            default:    nleaf = 8;   loff = t * 80;  lsz = 80;  break;  // 640
        }
        if (t < nleaf) ls[t] = leaf_abs_sum(src + loff, lsz);
        __syncthreads();
        for (int m = nleaf >> 1; m >= 1; m >>= 1) {
            float v = 0.f;
            if (t < m) v = __fadd_rn(ls[2 * t], ls[2 * t + 1]);
            __syncthreads();
            if (t < m) ls[t] = v;
            __syncthreads();
        }
        const float alpha = __fdiv_rn(ls[0], (float)n);
        for (int i = t; i < n; i += 256) {
            const float w = src[i];
            const float sg = (w > 0.f) ? 1.f : ((w < 0.f) ? -1.f : 0.f);
            const int d = (i % K) * W + (i / K);
            ws[off + d] = __fmul_rn(sg, alpha);
        }
    }
}

// ---------------------------------------------------------------------------
// Fused forward: one block (256 threads) per image, strict fp32.
// LDS total 30,368 B -> 5 blocks/CU; VGPR capped at 64 -> 8 waves/SIMD OK.
// ---------------------------------------------------------------------------
__global__ __launch_bounds__(256, 8) void fused_kernel(
    const float* __restrict__ x, const float* __restrict__ ws,
    float* __restrict__ out)
{
    __shared__ __align__(16) float s_x[16][20];        //  1280 B
    __shared__ __align__(16) float s_h1[16][14][20];   // 17920 B
    __shared__ float s_h2[16 * 156];                   //  9984 B (stride-13 rows)
    __shared__ float s_v96[96];                        //   384 B
    __shared__ float s_t96[96];                        //   384 B
    __shared__ float s_q[96];                          //   384 B
    __shared__ float s_r8[8];                          //    32 B

    const int b = blockIdx.x;
    const int t = threadIdx.x;

    // ---- Stage A: input act-quant (accumulation-free -> hard round) ----
    {
        const float v = x[b * 256 + t];
        float m = fabsf(v);
        #pragma unroll
        for (int msk = 8; msk >= 1; msk >>= 1) m = fmaxf(m, __shfl_xor(m, msk, 16));
        const float s = __fdiv_rn(127.0f, fmaxf(m, 1e-5f));
        float q = rintf(__fmul_rn(v, s));
        q = fminf(fmaxf(q, -128.f), 127.f);
        s_x[t >> 4][t & 15] = __fdiv_rn(q, s);
    }
    __syncthreads();

    // ---- Stage B: conv1 (1->16, 3x3) + ReLU + row quant (tie-neutral) ----
    if (t < 224) {
        const int oc = t / 14, oh = t % 14;
        const float* __restrict__ wg = ws + OFF_W1 + oc * 12;
        const float4 wv0 = *(const float4*)&wg[0];
        const float4 wv1 = *(const float4*)&wg[4];
        const float  w8  = wg[8];
        const float wr[9] = {wv0.x, wv0.y, wv0.z, wv0.w,
                             wv1.x, wv1.y, wv1.z, wv1.w, w8};
        float acc[14];
        #pragma unroll
        for (int ow = 0; ow < 14; ++ow) acc[ow] = 0.f;
        #pragma unroll
        for (int kh = 0; kh < 3; ++kh) {
            float A[16];
            *(float4*)&A[0]  = *(const float4*)&s_x[oh + kh][0];
            *(float4*)&A[4]  = *(const float4*)&s_x[oh + kh][4];
            *(float4*)&A[8]  = *(const float4*)&s_x[oh + kh][8];
            *(float4*)&A[12] = *(const float4*)&s_x[oh + kh][12];
            #pragma unroll
            for (int kw = 0; kw < 3; ++kw) {
                const float wk = wr[kh * 3 + kw];
                #pragma unroll
                for (int ow = 0; ow < 14; ++ow)
                    acc[ow] = __fmaf_rn(A[ow + kw], wk, acc[ow]);
            }
        }
        float mx = 0.f;
        #pragma unroll
        for (int ow = 0; ow < 14; ++ow) { acc[ow] = fmaxf(acc[ow], 0.f); mx = fmaxf(mx, acc[ow]); }
        const float s = __fdiv_rn(127.0f, fmaxf(mx, 1e-5f));
        float q[14];
        #pragma unroll
        for (int ow = 0; ow < 14; ++ow) q[ow] = quantq(acc[ow], s);
        *(float4*)&s_h1[oc][oh][0]  = *(const float4*)&q[0];
        *(float4*)&s_h1[oc][oh][4]  = *(const float4*)&q[4];
        *(float4*)&s_h1[oc][oh][8]  = *(const float4*)&q[8];
        *(float2*)&s_h1[oc][oh][12] = *(const float2*)&q[12];
    }
    __syncthreads();

    // ---- Stage C: conv1b (16->16, 3x3) + ReLU + row quant (tie-neutral) ----
    if (t < 192) {
        const int oc = t / 12, oh = t % 12;
        const float* __restrict__ wg = ws + OFF_W1B + oc * 192;
        float acc[12];
        #pragma unroll
        for (int i = 0; i < 12; ++i) acc[i] = 0.f;
        for (int ic = 0; ic < 16; ++ic) {
            const float4 wv0 = *(const float4*)&wg[ic * 12];
            const float4 wv1 = *(const float4*)&wg[ic * 12 + 4];
            const float  w8  = wg[ic * 12 + 8];
            const float wr[9] = {wv0.x, wv0.y, wv0.z, wv0.w,
                                 wv1.x, wv1.y, wv1.z, wv1.w, w8};
            #pragma unroll
            for (int kh = 0; kh < 3; ++kh) {
                float A[14];
                *(float4*)&A[0]  = *(const float4*)&s_h1[ic][oh + kh][0];
                *(float4*)&A[4]  = *(const float4*)&s_h1[ic][oh + kh][4];
                *(float4*)&A[8]  = *(const float4*)&s_h1[ic][oh + kh][8];
                *(float2*)&A[12] = *(const float2*)&s_h1[ic][oh + kh][12];
                #pragma unroll
                for (int kw = 0; kw < 3; ++kw) {
                    const float w = wr[kh * 3 + kw];
                    #pragma unroll
                    for (int ow = 0; ow < 12; ++ow)
                        acc[ow] = __fmaf_rn(A[ow + kw], w, acc[ow]);
                }
            }
        }
        float mx = 0.f;
        #pragma unroll
        for (int ow = 0; ow < 12; ++ow) { acc[ow] = fmaxf(acc[ow], 0.f); mx = fmaxf(mx, acc[ow]); }
        const float s = __fdiv_rn(127.0f, fmaxf(mx, 1e-5f));
        const int hb = oc * 156 + oh * 13;
        #pragma unroll
        for (int ow = 0; ow < 12; ++ow)
            s_h2[hb + ow] = quantq(acc[ow], s);
    }
    __syncthreads();

    // ---- Stage D: conv2 grouped binary (16 groups x 6 oc, 12x12) + ReLU ----
    if (t < 96) {
        const int g = t / 6;
        const float* __restrict__ wp = ws + OFF_W2;  // transposed: [k=144][96 oc]
        float acc = 0.f;
        #pragma unroll
        for (int r = 0; r < 12; ++r) {
            const int hb = g * 156 + r * 13;
            #pragma unroll
            for (int c = 0; c < 12; ++c)
                acc = __fmaf_rn(s_h2[hb + c], wp[(r * 12 + c) * 96 + t], acc);
        }
        s_v96[t] = fmaxf(acc, 0.f);
    }
    __syncthreads();

    // ================= fc section: ENTIRELY wave 0, no barriers =============
    if (t >= 64) return;   // waves 1-3 retire

    // ---- Stage E: fc1 (96->64) ----
    float u;   // current activation vector element (lane t holds element t)
    {
        const float va = s_v96[t];
        const float vb = (t < 32) ? s_v96[64 + t] : 0.f;
        s_t96[t] = __fmul_rn(va, va);
        if (t < 32) s_t96[64 + t] = __fmul_rn(vb, vb);
        if (t < 8) {
            float r = s_t96[t];
            for (int i = 8; i < 96; i += 8) r = __fadd_rn(r, s_t96[i + t]);
            s_r8[t] = r;
        }
        // all lanes redundantly compute the tree -> identical bits, no broadcast
        const float c = __fadd_rn(
            __fadd_rn(__fadd_rn(s_r8[0], s_r8[1]), __fadd_rn(s_r8[2], s_r8[3])),
            __fadd_rn(__fadd_rn(s_r8[4], s_r8[5]), __fadd_rn(s_r8[6], s_r8[7])));
        const float mean = __fdiv_rn(c, 96.0f);
        const float bc1 = __fdiv_rn(1.0f, __fsqrt_rn(__fadd_rn(mean, 1e-6f)));
        const float n0 = __fmul_rn(va, bc1);
        const float n1 = __fmul_rn(vb, bc1);       // valid for t<32
        float m = n0;
        if (t < 32) m = fmaxf(m, n1);
        #pragma unroll
        for (int msk = 32; msk >= 1; msk >>= 1) m = fmaxf(m, __shfl_xor(m, msk, 64));
        const float s2 = __fdiv_rn(127.0f, fmaxf(m, 1e-5f));
        s_q[t] = quantq(n0, s2);
        if (t < 32) s_q[64 + t] = quantq(n1, s2);
        const float* __restrict__ wp = ws + OFF_F1;  // [k=96][64 o]
        float acc = 0.f;
        for (int k = 0; k < 96; ++k) acc = __fmaf_rn(s_q[k], wp[k * 64 + t], acc);
        u = fmaxf(acc, 0.f);
    }

    // ---- Stages F,G: fc2, fc3 (64->64) ----
    #pragma unroll 1
    for (int stage = 0; stage < 2; ++stage) {
        const int woff = stage == 0 ? OFF_F2 : OFF_F3;
        s_t96[t] = __fmul_rn(u, u);
        if (t < 8) {
            float r = s_t96[t];
            for (int i = 8; i < 64; i += 8) r = __fadd_rn(r, s_t96[i + t]);
            s_r8[t] = r;
        }
        const float c = __fadd_rn(
            __fadd_rn(__fadd_rn(s_r8[0], s_r8[1]), __fadd_rn(s_r8[2], s_r8[3])),
            __fadd_rn(__fadd_rn(s_r8[4], s_r8[5]), __fadd_rn(s_r8[6], s_r8[7])));
        const float mean = __fdiv_rn(c, 64.0f);
        const float bc1 = __fdiv_rn(1.0f, __fsqrt_rn(__fadd_rn(mean, 1e-6f)));
        const float n0 = __fmul_rn(u, bc1);
        float m = n0;
        #pragma unroll
        for (int msk = 32; msk >= 1; msk >>= 1) m = fmaxf(m, __shfl_xor(m, msk, 64));
        const float s2 = __fdiv_rn(127.0f, fmaxf(m, 1e-5f));
        s_q[t] = quantq(n0, s2);
        const float* __restrict__ wp = ws + woff;    // [k=64][64 o]
        float acc = 0.f;
        for (int k = 0; k < 64; ++k) acc = __fmaf_rn(s_q[k], wp[k * 64 + t], acc);
        u = fmaxf(acc, 0.f);
    }

    // ---- Stage H: fcl (64->10), no ReLU ----
    {
        s_t96[t] = __fmul_rn(u, u);
        if (t < 8) {
            float r = s_t96[t];
            for (int i = 8; i < 64; i += 8) r = __fadd_rn(r, s_t96[i + t]);
            s_r8[t] = r;
        }
        const float c = __fadd_rn(
            __fadd_rn(__fadd_rn(s_r8[0], s_r8[1]), __fadd_rn(s_r8[2], s_r8[3])),
            __fadd_rn(__fadd_rn(s_r8[4], s_r8[5]), __fadd_rn(s_r8[6], s_r8[7])));
        const float mean = __fdiv_rn(c, 64.0f);
        const float bc1 = __fdiv_rn(1.0f, __fsqrt_rn(__fadd_rn(mean, 1e-6f)));
        const float n0 = __fmul_rn(u, bc1);
        float m = n0;
        #pragma unroll
        for (int msk = 32; msk >= 1; msk >>= 1) m = fmaxf(m, __shfl_xor(m, msk, 64));
        const float s2 = __fdiv_rn(127.0f, fmaxf(m, 1e-5f));
        s_q[t] = quantq(n0, s2);
        const int to = (t < 10) ? t : 9;             // clamp: avoid OOB reads
        const float* __restrict__ wp = ws + OFF_FL;  // [k=64][10 o]
        float acc = 0.f;
        for (int k = 0; k < 64; ++k) acc = __fmaf_rn(s_q[k], wp[k * 10 + to], acc);
        if (t < 10) out[b * 10 + t] = acc;
    }
}

extern "C" void kernel_launch(void* const* d_in, const int* in_sizes, int n_in,
                              void* d_out, int out_size, void* d_ws, size_t ws_size,
                              hipStream_t stream) {
    const float* x   = (const float*)d_in[0];
    const float* w1  = (const float*)d_in[1];
    const float* w1b = (const float*)d_in[2];
    const float* w2  = (const float*)d_in[3];
    const float* f1  = (const float*)d_in[4];
    const float* f2  = (const float*)d_in[5];
    const float* f3  = (const float*)d_in[6];
    const float* fl  = (const float*)d_in[7];
    float* out = (float*)d_out;
    float* ws  = (float*)d_ws;

    const int B = in_sizes[0] / 256;  // 8192

    wq_kernel<<<7, 256, 0, stream>>>(w1, w1b, w2, f1, f2, f3, fl, ws);
    fused_kernel<<<B, 256, 0, stream>>>(x, ws, out);
}